// Round 8
// baseline (248.280 us; speedup 1.0000x reference)
//
#include <hip/hip_runtime.h>
#include <hip/hip_bf16.h>

typedef __bf16 bf16_t;
typedef bf16_t bf16x8 __attribute__((ext_vector_type(8)));
typedef float f32x4 __attribute__((ext_vector_type(4)));

#define NB 2
#define SEQ 2048
#define DIM 1024
#define NH 32
#define HDIM 32

#define LDA 40  // attn LDS pad stride

static __device__ __forceinline__ f32x4 mfma16(bf16x8 a, bf16x8 b, f32x4 c) {
    return __builtin_amdgcn_mfma_f32_16x16x32_bf16(a, b, c, 0, 0, 0);
}

// async global->LDS, 16B per lane; lds dest = wave-uniform base + lane*16
static __device__ __forceinline__ void load_lds16(const bf16_t* g, bf16_t* l) {
    __builtin_amdgcn_global_load_lds(
        (const __attribute__((address_space(1))) void*)(g),
        (__attribute__((address_space(3))) void*)(l), 16, 0, 0);
}

// ---------------------------------------------------------------------------
// fp32 -> bf16 convert. 5 regions (x, wq, wk, wv, wo), grid-stride.
// ---------------------------------------------------------------------------
__global__ __launch_bounds__(256)
void cvt_f32_bf16(const float* __restrict__ s0, bf16_t* __restrict__ d0, int n0,
                  const float* __restrict__ s1, bf16_t* __restrict__ d1, int n1,
                  const float* __restrict__ s2, bf16_t* __restrict__ d2, int n2,
                  const float* __restrict__ s3, bf16_t* __restrict__ d3, int n3,
                  const float* __restrict__ s4, bf16_t* __restrict__ d4, int n4) {
    const int stride = gridDim.x * blockDim.x;
    const int tid = blockIdx.x * blockDim.x + threadIdx.x;
    const float* src[5] = {s0, s1, s2, s3, s4};
    bf16_t* dst[5] = {d0, d1, d2, d3, d4};
    const int n[5] = {n0, n1, n2, n3, n4};
#pragma unroll
    for (int r = 0; r < 5; r++) {
        const int nv = n[r] >> 2;
        for (int i = tid; i < nv; i += stride) {
            float4 v = ((const float4*)src[r])[i];
            bf16_t o[4] = {(bf16_t)v.x, (bf16_t)v.y, (bf16_t)v.z, (bf16_t)v.w};
            *(uint2*)(dst[r] + i * 4) = *(const uint2*)o;
        }
    }
}

// ---------------------------------------------------------------------------
// m97-structure GEMM: C = A @ W^T, all-bf16, BM=128, BN={128,64}, BK=32,
// 4 waves (2x2), global_load_lds 16B staging, 2-barrier K-loop.
// __launch_bounds__(256,3): cap VGPR for 3 blocks/CU (m97 occupancy point).
// EPI 0: out-proj -> fp32 row-major C[M][DIM]  (use BN=64: 512 blocks)
// EPI 1: fused QKV (W=[wq;wk;wv], N=3072, BN=128): seg0->qb, seg1->kb
//        (head-split), seg2->vtb (swapped-operand MFMA, transposed store)
// ---------------------------------------------------------------------------
template <int EPI, int BN>
__global__ __launch_bounds__(256, 3)
void gemm_mn(const bf16_t* __restrict__ A, const bf16_t* __restrict__ W,
             float* __restrict__ Cf, bf16_t* __restrict__ qb,
             bf16_t* __restrict__ kb, bf16_t* __restrict__ vtb) {
    constexpr int NI = BN / 32;  // b-frags per wave
    __shared__ alignas(16) bf16_t As[128 * 32];
    __shared__ alignas(16) bf16_t Bs[BN * 32];
    const int t = threadIdx.x;
    const int lane = t & 63, wave = t >> 6;
    const int lane16 = lane & 15, quad = lane >> 4;
    const int wm = (wave >> 1) * 64, wn = (wave & 1) * (BN / 2);
    const int m0 = blockIdx.y * 128;
    const int n0g = blockIdx.x * BN;
    const int tr = t >> 2;        // 0..63
    const int tc = (t & 3) * 8;   // 0,8,16,24
    bf16_t* ldsA = As + (t & 192) * 8;  // wave-uniform base (lane*16B by HW)
    bf16_t* ldsB = Bs + (t & 192) * 8;
    const bf16_t* ga = A + (m0 + tr) * DIM + tc;
    const bf16_t* gb = W + (n0g + tr) * DIM + tc;

    const bool vseg = (EPI == 1) && (n0g >= 2048);

    f32x4 acc[4][NI];
#pragma unroll
    for (int i = 0; i < 4; i++)
#pragma unroll
        for (int j = 0; j < NI; j++) acc[i][j] = f32x4{0.f, 0.f, 0.f, 0.f};

    for (int k0 = 0; k0 < DIM; k0 += 32) {
        __syncthreads();  // prev iteration's frag reads done
        load_lds16(ga + k0, ldsA);
        load_lds16(ga + 64 * DIM + k0, ldsA + 64 * 32);
        load_lds16(gb + k0, ldsB);
        if (BN == 128) load_lds16(gb + 64 * DIM + k0, ldsB + 64 * 32);
        __syncthreads();  // vmcnt drained by compiler before barrier
        bf16x8 af[4], bfr[NI];
#pragma unroll
        for (int mi = 0; mi < 4; mi++)
            af[mi] = *(const bf16x8*)(As + (wm + mi * 16 + lane16) * 32 + quad * 8);
#pragma unroll
        for (int ni = 0; ni < NI; ni++)
            bfr[ni] = *(const bf16x8*)(Bs + (wn + ni * 16 + lane16) * 32 + quad * 8);
        if (vseg) {
#pragma unroll
            for (int mi = 0; mi < 4; mi++)
#pragma unroll
                for (int ni = 0; ni < NI; ni++)
                    acc[mi][ni] = mfma16(bfr[ni], af[mi], acc[mi][ni]);
        } else {
#pragma unroll
            for (int mi = 0; mi < 4; mi++)
#pragma unroll
                for (int ni = 0; ni < NI; ni++)
                    acc[mi][ni] = mfma16(af[mi], bfr[ni], acc[mi][ni]);
        }
    }

    if (EPI == 0) {
#pragma unroll
        for (int mi = 0; mi < 4; mi++)
#pragma unroll
            for (int ni = 0; ni < NI; ni++)
#pragma unroll
                for (int r = 0; r < 4; r++) {
                    int row = m0 + wm + mi * 16 + quad * 4 + r;
                    int col = n0g + wn + ni * 16 + lane16;
                    Cf[row * DIM + col] = acc[mi][ni][r];
                }
    } else if (!vseg) {
        bf16_t* dst = (n0g < 1024) ? qb : kb;
        const int nb = n0g & 1023;
#pragma unroll
        for (int mi = 0; mi < 4; mi++)
#pragma unroll
            for (int ni = 0; ni < NI; ni++)
#pragma unroll
                for (int r = 0; r < 4; r++) {
                    int m = m0 + wm + mi * 16 + quad * 4 + r;  // b*SEQ+s
                    int nl = nb + wn + ni * 16 + lane16;       // h*HDIM+hd
                    int b = m >> 11, s = m & (SEQ - 1);
                    int h = nl >> 5, d = nl & 31;
                    dst[(((b * NH + h) << 11) + s) * 32 + d] = (bf16_t)acc[mi][ni][r];
                }
    } else {  // V: acc = C^T tile; row(quad,r)=n(hd), col(lane16)=m(s)
        const int nb = n0g & 1023;
#pragma unroll
        for (int mi = 0; mi < 4; mi++)
#pragma unroll
            for (int ni = 0; ni < NI; ni++)
#pragma unroll
                for (int r = 0; r < 4; r++) {
                    int nl = nb + wn + ni * 16 + quad * 4 + r;  // h*HDIM+hd
                    int m = m0 + wm + mi * 16 + lane16;         // b*SEQ+s
                    int b = m >> 11, s = m & (SEQ - 1);
                    int h = nl >> 5, d = nl & 31;
                    vtb[(((b * NH + h) << 5) + d) * SEQ + s] = (bf16_t)acc[mi][ni][r];
                }
    }
}

// ---------------------------------------------------------------------------
// Flash attention, causal, SSMax. No online max (scores bounded; p,l share
// the implicit e^m factor). __expf (v_mul+v_exp — exp2f is OCML slow path,
// R7 regression). Keys permuted even/odd so (p0,p1) pack into one
// ds_write_b32. Diagonal block peeled. K prefetch one block ahead.
// ---------------------------------------------------------------------------
__global__ __launch_bounds__(256)
void attn_fwd(const bf16_t* __restrict__ q, const bf16_t* __restrict__ k,
              const bf16_t* __restrict__ vt, const float* __restrict__ slen,
              const float* __restrict__ sscale, bf16_t* __restrict__ out) {
    __shared__ alignas(16) bf16_t pscr[4][32 * LDA];
    const int t = threadIdx.x;
    const int lane = t & 63, wave = t >> 6;
    const int lane16 = lane & 15, quad = lane >> 4;
    const int gw = blockIdx.x * 4 + wave;  // 0..4095
    const int idx = gw & 63;
    const int qt = (idx & 1) ? (63 - (idx >> 1)) : (idx >> 1);
    const int h = (gw >> 6) & (NH - 1);
    const int b = gw >> 11;
    const int q0 = qt * 32;
    const bf16_t* qh = q + (b * NH + h) * SEQ * HDIM;
    const bf16_t* kh = k + (b * NH + h) * SEQ * HDIM;
    const bf16_t* vth = vt + (b * NH + h) * HDIM * SEQ;
    bf16_t* psw = pscr[wave];

    bf16x8 qf[2];
    qf[0] = *(const bf16x8*)(qh + (q0 + lane16) * HDIM + quad * 8);
    qf[1] = *(const bf16x8*)(qh + (q0 + 16 + lane16) * HDIM + quad * 8);

    const float hs = sscale[h] * 0.17677669529663687f;  // 1/sqrt(32)
    float rs[2][4];
#pragma unroll
    for (int mi = 0; mi < 2; mi++)
#pragma unroll
        for (int r = 0; r < 4; r++)
            rs[mi][r] = slen[q0 + mi * 16 + quad * 4 + r] * hs;

    f32x4 o[2][2];
    float lrow[2][4];
#pragma unroll
    for (int mi = 0; mi < 2; mi++)
#pragma unroll
        for (int r = 0; r < 4; r++) lrow[mi][r] = 0.f;
#pragma unroll
    for (int mi = 0; mi < 2; mi++)
#pragma unroll
        for (int ni = 0; ni < 2; ni++) o[mi][ni] = f32x4{0.f, 0.f, 0.f, 0.f};

    const bf16_t* kp0 = kh + (2 * lane16) * HDIM + quad * 8;
    const bf16_t* vp0 = vth + lane16 * SEQ + quad * 8;
    const bf16_t* vp1 = vth + (16 + lane16) * SEQ + quad * 8;

    auto process = [&](bf16x8 kf0, bf16x8 kf1, int kv, bool domask) {
        const f32x4 zz = f32x4{0.f, 0.f, 0.f, 0.f};
        f32x4 sc[2][2];
        sc[0][0] = mfma16(qf[0], kf0, zz);
        sc[0][1] = mfma16(qf[0], kf1, zz);
        sc[1][0] = mfma16(qf[1], kf0, zz);
        sc[1][1] = mfma16(qf[1], kf1, zz);
        bf16x8 vf0 = *(const bf16x8*)(vp0 + kv);
        bf16x8 vf1 = *(const bf16x8*)(vp1 + kv);
#pragma unroll
        for (int mi = 0; mi < 2; mi++)
#pragma unroll
            for (int r = 0; r < 4; r++) {
                float p0 = __expf(sc[mi][0][r] * rs[mi][r]);  // key kv+2*l16
                float p1 = __expf(sc[mi][1][r] * rs[mi][r]);  // key kv+2*l16+1
                if (domask) {
                    const int rowloc = mi * 16 + quad * 4 + r;
                    if (2 * lane16 > rowloc) p0 = 0.f;
                    if (2 * lane16 + 1 > rowloc) p1 = 0.f;
                }
                lrow[mi][r] += p0 + p1;
                bf16_t pb[2] = {(bf16_t)p0, (bf16_t)p1};
                *(unsigned int*)(psw + (mi * 16 + quad * 4 + r) * LDA +
                                 2 * lane16) = *(const unsigned int*)pb;
            }
        asm volatile("s_waitcnt lgkmcnt(0)" ::: "memory");
        bf16x8 pf0 = *(const bf16x8*)(psw + lane16 * LDA + quad * 8);
        bf16x8 pf1 = *(const bf16x8*)(psw + (16 + lane16) * LDA + quad * 8);
        o[0][0] = mfma16(pf0, vf0, o[0][0]);
        o[0][1] = mfma16(pf0, vf1, o[0][1]);
        o[1][0] = mfma16(pf1, vf0, o[1][0]);
        o[1][1] = mfma16(pf1, vf1, o[1][1]);
    };

    bf16x8 kc0 = *(const bf16x8*)(kp0);
    bf16x8 kc1 = *(const bf16x8*)(kp0 + HDIM);
    for (int kv = 0; kv < q0; kv += 32) {
        bf16x8 kn0 = *(const bf16x8*)(kp0 + (kv + 32) * HDIM);
        bf16x8 kn1 = *(const bf16x8*)(kp0 + (kv + 32) * HDIM + HDIM);
        process(kc0, kc1, kv, false);
        kc0 = kn0;
        kc1 = kn1;
    }
    process(kc0, kc1, q0, true);  // diagonal block

#pragma unroll
    for (int mi = 0; mi < 2; mi++)
#pragma unroll
        for (int r = 0; r < 4; r++) {
            float l = lrow[mi][r];
#pragma unroll
            for (int off = 1; off < 16; off <<= 1) l += __shfl_xor(l, off);
            float inv = 1.0f / l;
            int qi = q0 + mi * 16 + quad * 4 + r;
            bf16_t* ob = out + (b * SEQ + qi) * DIM + h * HDIM;
#pragma unroll
            for (int ni = 0; ni < 2; ni++)
                ob[ni * 16 + lane16] = (bf16_t)(o[mi][ni][r] * inv);
        }
}

extern "C" void kernel_launch(void* const* d_in, const int* in_sizes, int n_in,
                              void* d_out, int out_size, void* d_ws, size_t ws_size,
                              hipStream_t stream) {
    // input order: x, mask, section_log_len, wq, wk, wv, wo, seq_scale
    // dtype model (verified): fp32 I/O, bf16 internal compute.
    const float* x = (const float*)d_in[0];
    const float* slen = (const float*)d_in[2];
    const float* wq = (const float*)d_in[3];
    const float* wk = (const float*)d_in[4];
    const float* wv = (const float*)d_in[5];
    const float* wo = (const float*)d_in[6];
    const float* ss = (const float*)d_in[7];

    const size_t ELEMS = (size_t)NB * SEQ * DIM;  // 4 Mi elems
    const size_t WELEMS = (size_t)DIM * DIM;      // 1 Mi elems
    // ws layout (bf16 elems), 32 MB (>=41 MB available per R3):
    // xb/abuf 4M | wqkvb 3M | wob 1M | qbuf 4M | vtbuf 4M
    bf16_t* xb = (bf16_t*)d_ws;           // phase 1: bf16 x
    bf16_t* abuf = xb;                    // phase 2: attn out
    bf16_t* wqkvb = xb + ELEMS;           // packed [wq;wk;wv], N=3072
    bf16_t* wob = wqkvb + 3 * WELEMS;
    bf16_t* qbuf = wob + WELEMS;          // (B,H,S,HD)
    bf16_t* vtbuf = qbuf + ELEMS;         // (B,H,HD,S)
    bf16_t* kbuf = (bf16_t*)d_out;        // 8 MB of 16 MB fp32 out (scratch)

    dim3 blk(256);
    cvt_f32_bf16<<<dim3(1024), blk, 0, stream>>>(
        x, xb, (int)ELEMS, wq, wqkvb, (int)WELEMS, wk, wqkvb + WELEMS,
        (int)WELEMS, wv, wqkvb + 2 * WELEMS, (int)WELEMS, wo, wob, (int)WELEMS);

    gemm_mn<1, 128><<<dim3(3 * DIM / 128, (NB * SEQ) / 128), blk, 0, stream>>>(
        xb, wqkvb, nullptr, qbuf, kbuf, vtbuf);
    attn_fwd<<<dim3(NB * NH * (SEQ / 32) / 4), blk, 0, stream>>>(
        qbuf, kbuf, vtbuf, slen, ss, abuf);
    gemm_mn<0, 64><<<dim3(DIM / 64, (NB * SEQ) / 128), blk, 0, stream>>>(
        abuf, wob, (float*)d_out, nullptr, nullptr, nullptr);
}

// Round 9
// 221.316 us; speedup vs baseline: 1.1218x; 1.1218x over previous
//
#include <hip/hip_runtime.h>
#include <hip/hip_bf16.h>

typedef __bf16 bf16_t;
typedef bf16_t bf16x8 __attribute__((ext_vector_type(8)));
typedef float f32x4 __attribute__((ext_vector_type(4)));

#define NB 2
#define SEQ 2048
#define DIM 1024
#define NH 32
#define HDIM 32

#define LDA 40  // attn LDS pad stride

static __device__ __forceinline__ f32x4 mfma16(bf16x8 a, bf16x8 b, f32x4 c) {
    return __builtin_amdgcn_mfma_f32_16x16x32_bf16(a, b, c, 0, 0, 0);
}

// async global->LDS, 16B per lane; lds dest = wave-uniform base + lane*16
static __device__ __forceinline__ void load_lds16(const bf16_t* g, bf16_t* l) {
    __builtin_amdgcn_global_load_lds(
        (const __attribute__((address_space(1))) void*)(g),
        (__attribute__((address_space(3))) void*)(l), 16, 0, 0);
}

// ---------------------------------------------------------------------------
// fp32 -> bf16 convert. 5 regions (x, wq, wk, wv, wo), grid-stride.
// ---------------------------------------------------------------------------
__global__ __launch_bounds__(256)
void cvt_f32_bf16(const float* __restrict__ s0, bf16_t* __restrict__ d0, int n0,
                  const float* __restrict__ s1, bf16_t* __restrict__ d1, int n1,
                  const float* __restrict__ s2, bf16_t* __restrict__ d2, int n2,
                  const float* __restrict__ s3, bf16_t* __restrict__ d3, int n3,
                  const float* __restrict__ s4, bf16_t* __restrict__ d4, int n4) {
    const int stride = gridDim.x * blockDim.x;
    const int tid = blockIdx.x * blockDim.x + threadIdx.x;
    const float* src[5] = {s0, s1, s2, s3, s4};
    bf16_t* dst[5] = {d0, d1, d2, d3, d4};
    const int n[5] = {n0, n1, n2, n3, n4};
#pragma unroll
    for (int r = 0; r < 5; r++) {
        const int nv = n[r] >> 2;
        for (int i = tid; i < nv; i += stride) {
            float4 v = ((const float4*)src[r])[i];
            bf16_t o[4] = {(bf16_t)v.x, (bf16_t)v.y, (bf16_t)v.z, (bf16_t)v.w};
            *(uint2*)(dst[r] + i * 4) = *(const uint2*)o;
        }
    }
}

// ---------------------------------------------------------------------------
// GEMM: C = A @ W^T, all-bf16, BM=BN=128, BK=64 (two 32-col LDS panels per
// iter -> half the barrier drains of BK=32, 32 MFMA/wave between drains).
// XCD-swizzled block mapping: XCD c owns M-panels {c, c+8, c+16, c+24}
// (1 MB of A per XCD L2), streams W. 1-D grid, id&7 = XCD (dispatch
// round-robin heuristic; speed-only).
// EPI 0: out-proj -> fp32 row-major C[M][DIM]
// EPI 1: fused QKV (W=[wq;wk;wv], N=3072): seg0->qb, seg1->kb (head-split),
//        seg2->vtb (swapped-operand MFMA, transposed store)
// ---------------------------------------------------------------------------
template <int EPI>
__global__ __launch_bounds__(256)
void gemm_k64(const bf16_t* __restrict__ A, const bf16_t* __restrict__ W,
              float* __restrict__ Cf, bf16_t* __restrict__ qb,
              bf16_t* __restrict__ kb, bf16_t* __restrict__ vtb) {
    __shared__ alignas(16) bf16_t As[2 * 128 * 32];  // 16 KB (2 k-panels)
    __shared__ alignas(16) bf16_t Bs[2 * 128 * 32];  // 16 KB
    const int t = threadIdx.x;
    const int lane = t & 63;
    const int lane16 = lane & 15, quad = lane >> 4;
    const int wm = ((t >> 6) >> 1) * 64, wn = ((t >> 6) & 1) * 64;
    const int id = blockIdx.x;
    const int xcd = id & 7, slot = id >> 3;
    const int m0 = (xcd + 8 * (slot & 3)) * 128;
    const int n0g = (slot >> 2) * 128;
    const int tr = t >> 2;        // 0..63
    const int tc = (t & 3) * 8;   // 0,8,16,24
    bf16_t* ldsA = As + (t & 192) * 8;  // wave-uniform base (+lane*16B by HW)
    bf16_t* ldsB = Bs + (t & 192) * 8;
    const bf16_t* ga = A + (m0 + tr) * DIM + tc;
    const bf16_t* gb = W + (n0g + tr) * DIM + tc;
    const bool vseg = (EPI == 1) && (n0g >= 2048);

    f32x4 acc[4][4];
#pragma unroll
    for (int i = 0; i < 4; i++)
#pragma unroll
        for (int j = 0; j < 4; j++) acc[i][j] = f32x4{0.f, 0.f, 0.f, 0.f};

    for (int k0 = 0; k0 < DIM; k0 += 64) {
        __syncthreads();  // prev iteration's frag reads done
        load_lds16(ga + k0, ldsA);                       // A rows 0-63,  k panel 0
        load_lds16(ga + 64 * DIM + k0, ldsA + 2048);     // A rows 64-127,panel 0
        load_lds16(ga + k0 + 32, ldsA + 4096);           // A rows 0-63,  panel 1
        load_lds16(ga + 64 * DIM + k0 + 32, ldsA + 6144);
        load_lds16(gb + k0, ldsB);
        load_lds16(gb + 64 * DIM + k0, ldsB + 2048);
        load_lds16(gb + k0 + 32, ldsB + 4096);
        load_lds16(gb + 64 * DIM + k0 + 32, ldsB + 6144);
        __syncthreads();  // vmcnt drained by compiler before barrier
#pragma unroll
        for (int p = 0; p < 2; p++) {
            bf16x8 af[4], bfr[4];
#pragma unroll
            for (int mi = 0; mi < 4; mi++)
                af[mi] = *(const bf16x8*)(As + p * 4096 +
                                          (wm + mi * 16 + lane16) * 32 + quad * 8);
#pragma unroll
            for (int ni = 0; ni < 4; ni++)
                bfr[ni] = *(const bf16x8*)(Bs + p * 4096 +
                                           (wn + ni * 16 + lane16) * 32 + quad * 8);
            if (vseg) {
#pragma unroll
                for (int mi = 0; mi < 4; mi++)
#pragma unroll
                    for (int ni = 0; ni < 4; ni++)
                        acc[mi][ni] = mfma16(bfr[ni], af[mi], acc[mi][ni]);
            } else {
#pragma unroll
                for (int mi = 0; mi < 4; mi++)
#pragma unroll
                    for (int ni = 0; ni < 4; ni++)
                        acc[mi][ni] = mfma16(af[mi], bfr[ni], acc[mi][ni]);
            }
        }
    }

    if (EPI == 0) {
#pragma unroll
        for (int mi = 0; mi < 4; mi++)
#pragma unroll
            for (int ni = 0; ni < 4; ni++)
#pragma unroll
                for (int r = 0; r < 4; r++) {
                    int row = m0 + wm + mi * 16 + quad * 4 + r;
                    int col = n0g + wn + ni * 16 + lane16;
                    Cf[row * DIM + col] = acc[mi][ni][r];
                }
    } else if (!vseg) {
        bf16_t* dst = (n0g < 1024) ? qb : kb;
        const int nb = n0g & 1023;
#pragma unroll
        for (int mi = 0; mi < 4; mi++)
#pragma unroll
            for (int ni = 0; ni < 4; ni++)
#pragma unroll
                for (int r = 0; r < 4; r++) {
                    int m = m0 + wm + mi * 16 + quad * 4 + r;  // b*SEQ+s
                    int nl = nb + wn + ni * 16 + lane16;       // h*HDIM+hd
                    int b = m >> 11, s = m & (SEQ - 1);
                    int h = nl >> 5, d = nl & 31;
                    dst[(((b * NH + h) << 11) + s) * 32 + d] = (bf16_t)acc[mi][ni][r];
                }
    } else {  // V: acc = C^T tile; row(quad,r)=n(hd), col(lane16)=m(s)
        const int nb = n0g & 1023;
#pragma unroll
        for (int mi = 0; mi < 4; mi++)
#pragma unroll
            for (int ni = 0; ni < 4; ni++)
#pragma unroll
                for (int r = 0; r < 4; r++) {
                    int nl = nb + wn + ni * 16 + quad * 4 + r;  // h*HDIM+hd
                    int m = m0 + wm + mi * 16 + lane16;         // b*SEQ+s
                    int b = m >> 11, s = m & (SEQ - 1);
                    int h = nl >> 5, d = nl & 31;
                    vtb[(((b * NH + h) << 5) + d) * SEQ + s] = (bf16_t)acc[mi][ni][r];
                }
    }
}

// ---------------------------------------------------------------------------
// Flash attention, causal, SSMax. No online max (scores bounded; p,l share
// the implicit e^m factor). __expf fast path. Keys permuted even/odd so
// (p0,p1) pack into one ds_write_b32. Diagonal peeled. K prefetch.
// (Identical to R8's attn.)
// ---------------------------------------------------------------------------
__global__ __launch_bounds__(256)
void attn_fwd(const bf16_t* __restrict__ q, const bf16_t* __restrict__ k,
              const bf16_t* __restrict__ vt, const float* __restrict__ slen,
              const float* __restrict__ sscale, bf16_t* __restrict__ out) {
    __shared__ alignas(16) bf16_t pscr[4][32 * LDA];
    const int t = threadIdx.x;
    const int lane = t & 63, wave = t >> 6;
    const int lane16 = lane & 15, quad = lane >> 4;
    const int gw = blockIdx.x * 4 + wave;  // 0..4095
    const int idx = gw & 63;
    const int qt = (idx & 1) ? (63 - (idx >> 1)) : (idx >> 1);
    const int h = (gw >> 6) & (NH - 1);
    const int b = gw >> 11;
    const int q0 = qt * 32;
    const bf16_t* qh = q + (b * NH + h) * SEQ * HDIM;
    const bf16_t* kh = k + (b * NH + h) * SEQ * HDIM;
    const bf16_t* vth = vt + (b * NH + h) * HDIM * SEQ;
    bf16_t* psw = pscr[wave];

    bf16x8 qf[2];
    qf[0] = *(const bf16x8*)(qh + (q0 + lane16) * HDIM + quad * 8);
    qf[1] = *(const bf16x8*)(qh + (q0 + 16 + lane16) * HDIM + quad * 8);

    const float hs = sscale[h] * 0.17677669529663687f;  // 1/sqrt(32)
    float rs[2][4];
#pragma unroll
    for (int mi = 0; mi < 2; mi++)
#pragma unroll
        for (int r = 0; r < 4; r++)
            rs[mi][r] = slen[q0 + mi * 16 + quad * 4 + r] * hs;

    f32x4 o[2][2];
    float lrow[2][4];
#pragma unroll
    for (int mi = 0; mi < 2; mi++)
#pragma unroll
        for (int r = 0; r < 4; r++) lrow[mi][r] = 0.f;
#pragma unroll
    for (int mi = 0; mi < 2; mi++)
#pragma unroll
        for (int ni = 0; ni < 2; ni++) o[mi][ni] = f32x4{0.f, 0.f, 0.f, 0.f};

    const bf16_t* kp0 = kh + (2 * lane16) * HDIM + quad * 8;
    const bf16_t* vp0 = vth + lane16 * SEQ + quad * 8;
    const bf16_t* vp1 = vth + (16 + lane16) * SEQ + quad * 8;

    auto process = [&](bf16x8 kf0, bf16x8 kf1, int kv, bool domask) {
        const f32x4 zz = f32x4{0.f, 0.f, 0.f, 0.f};
        f32x4 sc[2][2];
        sc[0][0] = mfma16(qf[0], kf0, zz);
        sc[0][1] = mfma16(qf[0], kf1, zz);
        sc[1][0] = mfma16(qf[1], kf0, zz);
        sc[1][1] = mfma16(qf[1], kf1, zz);
        bf16x8 vf0 = *(const bf16x8*)(vp0 + kv);
        bf16x8 vf1 = *(const bf16x8*)(vp1 + kv);
#pragma unroll
        for (int mi = 0; mi < 2; mi++)
#pragma unroll
            for (int r = 0; r < 4; r++) {
                float p0 = __expf(sc[mi][0][r] * rs[mi][r]);  // key kv+2*l16
                float p1 = __expf(sc[mi][1][r] * rs[mi][r]);  // key kv+2*l16+1
                if (domask) {
                    const int rowloc = mi * 16 + quad * 4 + r;
                    if (2 * lane16 > rowloc) p0 = 0.f;
                    if (2 * lane16 + 1 > rowloc) p1 = 0.f;
                }
                lrow[mi][r] += p0 + p1;
                bf16_t pb[2] = {(bf16_t)p0, (bf16_t)p1};
                *(unsigned int*)(psw + (mi * 16 + quad * 4 + r) * LDA +
                                 2 * lane16) = *(const unsigned int*)pb;
            }
        asm volatile("s_waitcnt lgkmcnt(0)" ::: "memory");
        bf16x8 pf0 = *(const bf16x8*)(psw + lane16 * LDA + quad * 8);
        bf16x8 pf1 = *(const bf16x8*)(psw + (16 + lane16) * LDA + quad * 8);
        o[0][0] = mfma16(pf0, vf0, o[0][0]);
        o[0][1] = mfma16(pf0, vf1, o[0][1]);
        o[1][0] = mfma16(pf1, vf0, o[1][0]);
        o[1][1] = mfma16(pf1, vf1, o[1][1]);
    };

    bf16x8 kc0 = *(const bf16x8*)(kp0);
    bf16x8 kc1 = *(const bf16x8*)(kp0 + HDIM);
    for (int kv = 0; kv < q0; kv += 32) {
        bf16x8 kn0 = *(const bf16x8*)(kp0 + (kv + 32) * HDIM);
        bf16x8 kn1 = *(const bf16x8*)(kp0 + (kv + 32) * HDIM + HDIM);
        process(kc0, kc1, kv, false);
        kc0 = kn0;
        kc1 = kn1;
    }
    process(kc0, kc1, q0, true);  // diagonal block

#pragma unroll
    for (int mi = 0; mi < 2; mi++)
#pragma unroll
        for (int r = 0; r < 4; r++) {
            float l = lrow[mi][r];
#pragma unroll
            for (int off = 1; off < 16; off <<= 1) l += __shfl_xor(l, off);
            float inv = 1.0f / l;
            int qi = q0 + mi * 16 + quad * 4 + r;
            bf16_t* ob = out + (b * SEQ + qi) * DIM + h * HDIM;
#pragma unroll
            for (int ni = 0; ni < 2; ni++)
                ob[ni * 16 + lane16] = (bf16_t)(o[mi][ni][r] * inv);
        }
}

extern "C" void kernel_launch(void* const* d_in, const int* in_sizes, int n_in,
                              void* d_out, int out_size, void* d_ws, size_t ws_size,
                              hipStream_t stream) {
    // input order: x, mask, section_log_len, wq, wk, wv, wo, seq_scale
    // dtype model (verified): fp32 I/O, bf16 internal compute.
    const float* x = (const float*)d_in[0];
    const float* slen = (const float*)d_in[2];
    const float* wq = (const float*)d_in[3];
    const float* wk = (const float*)d_in[4];
    const float* wv = (const float*)d_in[5];
    const float* wo = (const float*)d_in[6];
    const float* ss = (const float*)d_in[7];

    const size_t ELEMS = (size_t)NB * SEQ * DIM;  // 4 Mi elems
    const size_t WELEMS = (size_t)DIM * DIM;      // 1 Mi elems
    // ws layout (bf16 elems), 32 MB (>=41 MB available per R3):
    // xb/abuf 4M | wqkvb 3M | wob 1M | qbuf 4M | vtbuf 4M
    bf16_t* xb = (bf16_t*)d_ws;           // phase 1: bf16 x
    bf16_t* abuf = xb;                    // phase 2: attn out
    bf16_t* wqkvb = xb + ELEMS;           // packed [wq;wk;wv], N=3072
    bf16_t* wob = wqkvb + 3 * WELEMS;
    bf16_t* qbuf = wob + WELEMS;          // (B,H,S,HD)
    bf16_t* vtbuf = qbuf + ELEMS;         // (B,H,HD,S)
    bf16_t* kbuf = (bf16_t*)d_out;        // 8 MB of 16 MB fp32 out (scratch)

    dim3 blk(256);
    cvt_f32_bf16<<<dim3(1024), blk, 0, stream>>>(
        x, xb, (int)ELEMS, wq, wqkvb, (int)WELEMS, wk, wqkvb + WELEMS,
        (int)WELEMS, wv, wqkvb + 2 * WELEMS, (int)WELEMS, wo, wob, (int)WELEMS);

    // QKV: 768 blocks (3/CU), XCD-swizzled 1-D grid
    gemm_k64<1><<<dim3(768), blk, 0, stream>>>(xb, wqkvb, nullptr, qbuf, kbuf,
                                               vtbuf);
    attn_fwd<<<dim3(NB * NH * (SEQ / 32) / 4), blk, 0, stream>>>(
        qbuf, kbuf, vtbuf, slen, ss, abuf);
    // out-proj: 256 blocks, XCD-swizzled 1-D grid
    gemm_k64<0><<<dim3(256), blk, 0, stream>>>(abuf, wob, (float*)d_out,
                                               nullptr, nullptr, nullptr);
}

// Round 10
// 215.982 us; speedup vs baseline: 1.1495x; 1.0247x over previous
//
#include <hip/hip_runtime.h>
#include <hip/hip_bf16.h>

typedef __bf16 bf16_t;
typedef bf16_t bf16x8 __attribute__((ext_vector_type(8)));
typedef float f32x4 __attribute__((ext_vector_type(4)));

#define NB 2
#define SEQ 2048
#define DIM 1024
#define NH 32
#define HDIM 32

#define LDA 40  // attn LDS pad stride

static __device__ __forceinline__ f32x4 mfma16(bf16x8 a, bf16x8 b, f32x4 c) {
    return __builtin_amdgcn_mfma_f32_16x16x32_bf16(a, b, c, 0, 0, 0);
}

// async global->LDS, 16B per lane; lds dest = wave-uniform base + lane*16
static __device__ __forceinline__ void load_lds16(const bf16_t* g, bf16_t* l) {
    __builtin_amdgcn_global_load_lds(
        (const __attribute__((address_space(1))) void*)(g),
        (__attribute__((address_space(3))) void*)(l), 16, 0, 0);
}

// ---------------------------------------------------------------------------
// fp32 -> bf16 convert. 5 regions (x, wq, wk, wv, wo), grid-stride.
// ---------------------------------------------------------------------------
__global__ __launch_bounds__(256)
void cvt_f32_bf16(const float* __restrict__ s0, bf16_t* __restrict__ d0, int n0,
                  const float* __restrict__ s1, bf16_t* __restrict__ d1, int n1,
                  const float* __restrict__ s2, bf16_t* __restrict__ d2, int n2,
                  const float* __restrict__ s3, bf16_t* __restrict__ d3, int n3,
                  const float* __restrict__ s4, bf16_t* __restrict__ d4, int n4) {
    const int stride = gridDim.x * blockDim.x;
    const int tid = blockIdx.x * blockDim.x + threadIdx.x;
    const float* src[5] = {s0, s1, s2, s3, s4};
    bf16_t* dst[5] = {d0, d1, d2, d3, d4};
    const int n[5] = {n0, n1, n2, n3, n4};
#pragma unroll
    for (int r = 0; r < 5; r++) {
        const int nv = n[r] >> 2;
        for (int i = tid; i < nv; i += stride) {
            float4 v = ((const float4*)src[r])[i];
            bf16_t o[4] = {(bf16_t)v.x, (bf16_t)v.y, (bf16_t)v.z, (bf16_t)v.w};
            *(uint2*)(dst[r] + i * 4) = *(const uint2*)o;
        }
    }
}

// ---------------------------------------------------------------------------
// Pipelined GEMM: C = A @ W^T, all-bf16, BN=128, BK=32, double-buffered LDS
// with RAW s_barrier + fine vmcnt (prefetch stays in flight across the
// barrier -- the restructured K-loop; __syncthreads would drain vmcnt(0)).
// Per iter/wave: issue next panel (4 or 3 global_load_lds), vmcnt(LPI) =
// wait current buffer only, s_barrier, 8/6 ds_read_b128 + 16/8 MFMA,
// lgkmcnt(0) + s_barrier before overwrite.
// EPI 0 (BM=64):  out-proj -> fp32 C[M][DIM], 512 blocks.
// EPI 1 (BM=128): fused QKV (W=[wq;wk;wv], N=3072), 768 blocks:
//   seg0 -> qb PRE-SCALED by slen[s]*ss[h]/sqrt(32) (folded SSMax),
//   seg1 -> kb (head-split), seg2 -> vtb (swapped MFMA, transposed store).
// XCD-swizzled 1-D grid (id&7 = XCD): each XCD's A working set ~1 MB -> L2.
// ---------------------------------------------------------------------------
template <int EPI, int BM>
__global__ __launch_bounds__(256)
void gemm_pipe(const bf16_t* __restrict__ A, const bf16_t* __restrict__ W,
               float* __restrict__ Cf, bf16_t* __restrict__ qb,
               bf16_t* __restrict__ kb, bf16_t* __restrict__ vtb,
               const float* __restrict__ slen, const float* __restrict__ ss) {
    constexpr int MI = BM / 32;  // m-frags per wave
    __shared__ alignas(16) bf16_t As[2 * BM * 32];
    __shared__ alignas(16) bf16_t Bs[2 * 128 * 32];
    const int t = threadIdx.x;
    const int lane = t & 63, wave = t >> 6;
    const int lane16 = lane & 15, quad = lane >> 4;
    const int wm = (wave >> 1) * (BM / 2), wn = (wave & 1) * 64;
    const int id = blockIdx.x;
    int m0, n0g;
    if (EPI == 1) {  // 768 = 8 xcd * 4 mslot * 24 n
        const int xcd = id & 7, slot = id >> 3;
        m0 = (xcd + 8 * (slot & 3)) * 128;
        n0g = (slot >> 2) * 128;
    } else {  // 512 = 8 xcd * 8 mslot * 8 n
        const int xcd = id & 7, slot = id >> 3;
        m0 = (xcd + 8 * (slot & 7)) * 64;
        n0g = (slot >> 3) * 128;
    }
    const int tr = t >> 2;        // 0..63
    const int tc = (t & 3) * 8;   // 0,8,16,24
    const bf16_t* ga = A + (m0 + tr) * DIM + tc;
    const bf16_t* gb = W + (n0g + tr) * DIM + tc;
    const bool vseg = (EPI == 1) && (n0g >= 2048);

    f32x4 acc[MI][4];
#pragma unroll
    for (int i = 0; i < MI; i++)
#pragma unroll
        for (int j = 0; j < 4; j++) acc[i][j] = f32x4{0.f, 0.f, 0.f, 0.f};

    auto stage = [&](int k0, int buf) {
        bf16_t* a_dst = As + buf * (BM * 32) + (t & 192) * 8;
        bf16_t* b_dst = Bs + buf * 4096 + (t & 192) * 8;
        load_lds16(ga + k0, a_dst);
        if (BM == 128) load_lds16(ga + 64 * DIM + k0, a_dst + 2048);
        load_lds16(gb + k0, b_dst);
        load_lds16(gb + 64 * DIM + k0, b_dst + 2048);
    };
    auto compute = [&](int buf) {
        bf16x8 af[MI], bfr[4];
#pragma unroll
        for (int mi = 0; mi < MI; mi++)
            af[mi] = *(const bf16x8*)(As + buf * (BM * 32) +
                                      (wm + mi * 16 + lane16) * 32 + quad * 8);
#pragma unroll
        for (int ni = 0; ni < 4; ni++)
            bfr[ni] = *(const bf16x8*)(Bs + buf * 4096 +
                                       (wn + ni * 16 + lane16) * 32 + quad * 8);
        if (vseg) {
#pragma unroll
            for (int mi = 0; mi < MI; mi++)
#pragma unroll
                for (int ni = 0; ni < 4; ni++)
                    acc[mi][ni] = mfma16(bfr[ni], af[mi], acc[mi][ni]);
        } else {
#pragma unroll
            for (int mi = 0; mi < MI; mi++)
#pragma unroll
                for (int ni = 0; ni < 4; ni++)
                    acc[mi][ni] = mfma16(af[mi], bfr[ni], acc[mi][ni]);
        }
    };

    stage(0, 0);
#pragma unroll
    for (int k0 = 0; k0 < DIM; k0 += 32) {
        const int cur = (k0 >> 5) & 1;
        if (k0 + 32 < DIM) {
            stage(k0 + 32, cur ^ 1);
            // wait only the CURRENT buffer's loads; prefetch stays in flight
            if (BM == 128)
                asm volatile("s_waitcnt vmcnt(4)" ::: "memory");
            else
                asm volatile("s_waitcnt vmcnt(3)" ::: "memory");
        } else {
            asm volatile("s_waitcnt vmcnt(0)" ::: "memory");
        }
        asm volatile("s_barrier" ::: "memory");
        compute(cur);
        if (k0 + 32 < DIM) {
            asm volatile("s_waitcnt lgkmcnt(0)" ::: "memory");
            asm volatile("s_barrier" ::: "memory");  // reads done; safe to overwrite
        }
    }

    if (EPI == 0) {
#pragma unroll
        for (int mi = 0; mi < MI; mi++)
#pragma unroll
            for (int ni = 0; ni < 4; ni++)
#pragma unroll
                for (int r = 0; r < 4; r++) {
                    int row = m0 + wm + mi * 16 + quad * 4 + r;
                    int col = n0g + wn + ni * 16 + lane16;
                    Cf[row * DIM + col] = acc[mi][ni][r];
                }
    } else if (!vseg) {
        const bool isq = (n0g < 1024);
        bf16_t* dst = isq ? qb : kb;
        const int nb = n0g & 1023;
#pragma unroll
        for (int mi = 0; mi < MI; mi++)
#pragma unroll
            for (int ni = 0; ni < 4; ni++) {
                const int h = ((nb + wn) >> 5) + (ni >> 1);  // lane-uniform
                const float hscale =
                    isq ? ss[h] * 0.17677669529663687f : 0.f;
#pragma unroll
                for (int r = 0; r < 4; r++) {
                    int m = m0 + wm + mi * 16 + quad * 4 + r;  // b*SEQ+s
                    int nl = nb + wn + ni * 16 + lane16;       // h*HDIM+hd
                    int b = m >> 11, s = m & (SEQ - 1);
                    int d = nl & 31;
                    float v = acc[mi][ni][r];
                    if (isq) v *= slen[s] * hscale;  // folded SSMax scale
                    dst[(((b * NH + h) << 11) + s) * 32 + d] = (bf16_t)v;
                }
            }
    } else {  // V: acc = C^T tile; row(quad,r)=n(hd), col(lane16)=m(s)
        const int nb = n0g & 1023;
#pragma unroll
        for (int mi = 0; mi < MI; mi++)
#pragma unroll
            for (int ni = 0; ni < 4; ni++)
#pragma unroll
                for (int r = 0; r < 4; r++) {
                    int nl = nb + wn + ni * 16 + quad * 4 + r;  // h*HDIM+hd
                    int m = m0 + wm + mi * 16 + lane16;         // b*SEQ+s
                    int b = m >> 11, s = m & (SEQ - 1);
                    int h = nl >> 5, d = nl & 31;
                    vtb[(((b * NH + h) << 5) + d) * SEQ + s] = (bf16_t)acc[mi][ni][r];
                }
    }
}

// ---------------------------------------------------------------------------
// Flash attention, causal, SSMax PRE-FOLDED INTO Q (scores arrive scaled).
// No online max (scores bounded; p,l share the implicit e^m factor). __expf
// fast path. Keys permuted even/odd -> (p0,p1) pack into one ds_write_b32.
// Diagonal peeled. K prefetch one block ahead.
// ---------------------------------------------------------------------------
__global__ __launch_bounds__(256)
void attn_fwd(const bf16_t* __restrict__ q, const bf16_t* __restrict__ k,
              const bf16_t* __restrict__ vt, bf16_t* __restrict__ out) {
    __shared__ alignas(16) bf16_t pscr[4][32 * LDA];
    const int t = threadIdx.x;
    const int lane = t & 63, wave = t >> 6;
    const int lane16 = lane & 15, quad = lane >> 4;
    const int gw = blockIdx.x * 4 + wave;  // 0..4095
    const int idx = gw & 63;
    const int qt = (idx & 1) ? (63 - (idx >> 1)) : (idx >> 1);
    const int h = (gw >> 6) & (NH - 1);
    const int b = gw >> 11;
    const int q0 = qt * 32;
    const bf16_t* qh = q + (b * NH + h) * SEQ * HDIM;
    const bf16_t* kh = k + (b * NH + h) * SEQ * HDIM;
    const bf16_t* vth = vt + (b * NH + h) * HDIM * SEQ;
    bf16_t* psw = pscr[wave];

    bf16x8 qf[2];
    qf[0] = *(const bf16x8*)(qh + (q0 + lane16) * HDIM + quad * 8);
    qf[1] = *(const bf16x8*)(qh + (q0 + 16 + lane16) * HDIM + quad * 8);

    f32x4 o[2][2];
    float lrow[2][4];
#pragma unroll
    for (int mi = 0; mi < 2; mi++)
#pragma unroll
        for (int r = 0; r < 4; r++) lrow[mi][r] = 0.f;
#pragma unroll
    for (int mi = 0; mi < 2; mi++)
#pragma unroll
        for (int ni = 0; ni < 2; ni++) o[mi][ni] = f32x4{0.f, 0.f, 0.f, 0.f};

    const bf16_t* kp0 = kh + (2 * lane16) * HDIM + quad * 8;
    const bf16_t* vp0 = vth + lane16 * SEQ + quad * 8;
    const bf16_t* vp1 = vth + (16 + lane16) * SEQ + quad * 8;

    auto process = [&](bf16x8 kf0, bf16x8 kf1, int kv, bool domask) {
        const f32x4 zz = f32x4{0.f, 0.f, 0.f, 0.f};
        f32x4 sc[2][2];
        sc[0][0] = mfma16(qf[0], kf0, zz);
        sc[0][1] = mfma16(qf[0], kf1, zz);
        sc[1][0] = mfma16(qf[1], kf0, zz);
        sc[1][1] = mfma16(qf[1], kf1, zz);
        bf16x8 vf0 = *(const bf16x8*)(vp0 + kv);
        bf16x8 vf1 = *(const bf16x8*)(vp1 + kv);
#pragma unroll
        for (int mi = 0; mi < 2; mi++)
#pragma unroll
            for (int r = 0; r < 4; r++) {
                float p0 = __expf(sc[mi][0][r]);  // key kv+2*l16  (pre-scaled)
                float p1 = __expf(sc[mi][1][r]);  // key kv+2*l16+1
                if (domask) {
                    const int rowloc = mi * 16 + quad * 4 + r;
                    if (2 * lane16 > rowloc) p0 = 0.f;
                    if (2 * lane16 + 1 > rowloc) p1 = 0.f;
                }
                lrow[mi][r] += p0 + p1;
                bf16_t pb[2] = {(bf16_t)p0, (bf16_t)p1};
                *(unsigned int*)(psw + (mi * 16 + quad * 4 + r) * LDA +
                                 2 * lane16) = *(const unsigned int*)pb;
            }
        asm volatile("s_waitcnt lgkmcnt(0)" ::: "memory");
        bf16x8 pf0 = *(const bf16x8*)(psw + lane16 * LDA + quad * 8);
        bf16x8 pf1 = *(const bf16x8*)(psw + (16 + lane16) * LDA + quad * 8);
        o[0][0] = mfma16(pf0, vf0, o[0][0]);
        o[0][1] = mfma16(pf0, vf1, o[0][1]);
        o[1][0] = mfma16(pf1, vf0, o[1][0]);
        o[1][1] = mfma16(pf1, vf1, o[1][1]);
    };

    bf16x8 kc0 = *(const bf16x8*)(kp0);
    bf16x8 kc1 = *(const bf16x8*)(kp0 + HDIM);
    for (int kv = 0; kv < q0; kv += 32) {
        bf16x8 kn0 = *(const bf16x8*)(kp0 + (kv + 32) * HDIM);
        bf16x8 kn1 = *(const bf16x8*)(kp0 + (kv + 32) * HDIM + HDIM);
        process(kc0, kc1, kv, false);
        kc0 = kn0;
        kc1 = kn1;
    }
    process(kc0, kc1, q0, true);  // diagonal block

#pragma unroll
    for (int mi = 0; mi < 2; mi++)
#pragma unroll
        for (int r = 0; r < 4; r++) {
            float l = lrow[mi][r];
#pragma unroll
            for (int off = 1; off < 16; off <<= 1) l += __shfl_xor(l, off);
            float inv = 1.0f / l;
            int qi = q0 + mi * 16 + quad * 4 + r;
            bf16_t* ob = out + (b * SEQ + qi) * DIM + h * HDIM;
#pragma unroll
            for (int ni = 0; ni < 2; ni++)
                ob[ni * 16 + lane16] = (bf16_t)(o[mi][ni][r] * inv);
        }
}

extern "C" void kernel_launch(void* const* d_in, const int* in_sizes, int n_in,
                              void* d_out, int out_size, void* d_ws, size_t ws_size,
                              hipStream_t stream) {
    // input order: x, mask, section_log_len, wq, wk, wv, wo, seq_scale
    // dtype model (verified): fp32 I/O, bf16 internal compute.
    const float* x = (const float*)d_in[0];
    const float* slen = (const float*)d_in[2];
    const float* wq = (const float*)d_in[3];
    const float* wk = (const float*)d_in[4];
    const float* wv = (const float*)d_in[5];
    const float* wo = (const float*)d_in[6];
    const float* ss = (const float*)d_in[7];

    const size_t ELEMS = (size_t)NB * SEQ * DIM;  // 4 Mi elems
    const size_t WELEMS = (size_t)DIM * DIM;      // 1 Mi elems
    // ws layout (bf16 elems), 32 MB (>=41 MB available per R3):
    bf16_t* xb = (bf16_t*)d_ws;           // phase 1: bf16 x
    bf16_t* abuf = xb;                    // phase 2: attn out
    bf16_t* wqkvb = xb + ELEMS;           // packed [wq;wk;wv], N=3072
    bf16_t* wob = wqkvb + 3 * WELEMS;
    bf16_t* qbuf = wob + WELEMS;          // (B,H,S,HD), PRE-SCALED
    bf16_t* vtbuf = qbuf + ELEMS;         // (B,H,HD,S)
    bf16_t* kbuf = (bf16_t*)d_out;        // 8 MB of 16 MB fp32 out (scratch)

    dim3 blk(256);
    cvt_f32_bf16<<<dim3(1024), blk, 0, stream>>>(
        x, xb, (int)ELEMS, wq, wqkvb, (int)WELEMS, wk, wqkvb + WELEMS,
        (int)WELEMS, wv, wqkvb + 2 * WELEMS, (int)WELEMS, wo, wob, (int)WELEMS);

    // QKV: 768 blocks (3/CU), XCD-swizzled, pipelined K-loop
    gemm_pipe<1, 128><<<dim3(768), blk, 0, stream>>>(
        xb, wqkvb, nullptr, qbuf, kbuf, vtbuf, slen, ss);
    attn_fwd<<<dim3(NB * NH * (SEQ / 32) / 4), blk, 0, stream>>>(
        qbuf, kbuf, vtbuf, abuf);
    // out-proj: 512 blocks (2/CU), XCD-swizzled, pipelined K-loop
    gemm_pipe<0, 64><<<dim3(512), blk, 0, stream>>>(
        abuf, wob, (float*)d_out, nullptr, nullptr, nullptr, nullptr, nullptr);
}